// Round 8
// baseline (229.324 us; speedup 1.0000x reference)
//
#include <hip/hip_runtime.h>
#include <stdint.h>

#define TOKENS 16384
#define DDIM   1024
#define NEXP   64
#define NCOL   128            // 64 gate cols + 64 noise cols
#define MT     32             // tokens per block
#define KB     32             // k-tile
#define NBLK   (TOKENS / MT)  // 512 blocks

// -------- per-block loss partials in device globals (no d_ws) --------
__device__ float g_ps[NBLK][NEXP];   // sum of clean router probs per expert
__device__ float g_cnt[NBLK][NEXP];  // top-2 counts per expert
__device__ float g_sp[NBLK];         // sum of softplus(noise logits)

// ---------------- JAX threefry2x32 (20 rounds) ----------------
struct U2 { uint32_t a, b; };

__host__ __device__ constexpr U2 tf2x32(uint32_t k0, uint32_t k1,
                                        uint32_t x0, uint32_t x1) {
  uint32_t ks[3] = {k0, k1, k0 ^ k1 ^ 0x1BD11BDAu};
  const uint32_t rot[2][4] = {{13u, 15u, 26u, 6u}, {17u, 29u, 16u, 24u}};
  x0 += ks[0]; x1 += ks[1];
  for (int d = 0; d < 5; ++d) {
    for (int j = 0; j < 4; ++j) {
      uint32_t r = rot[d & 1][j];
      x0 += x1;
      x1 = (x1 << r) | (x1 >> (32u - r));
      x1 ^= x0;
    }
    x0 += ks[(d + 1) % 3];
    x1 += ks[(d + 2) % 3] + (uint32_t)(d + 1);
  }
  return U2{x0, x1};
}

// JAX >=0.5 default: jax_threefry_partitionable=True.
// bits[i] = fold(threefry(key, (hi32(i), lo32(i)))) ; for 32-bit output the
// two PRF words are xor-folded. n = 2^20 < 2^32 so hi32(i) = 0.
__device__ inline uint32_t noise_bits(uint32_t i) {
  constexpr U2 NK = tf2x32(0u, 0u, 0u, 12345u);   // fold_in(key(0), 12345)
  U2 o = tf2x32(NK.a, NK.b, 0u, i);
  return o.a ^ o.b;
}

// XLA ErfInv32 (Giles polynomial) — matches jax lax.erf_inv f32
__device__ inline float xla_erfinv(float x) {
  float w = -log1pf(-x * x);
  float p;
  if (w < 5.0f) {
    w = w - 2.5f;
    p = 2.81022636e-08f;
    p = 3.43273939e-07f + p * w;
    p = -3.5233877e-06f + p * w;
    p = -4.39150654e-06f + p * w;
    p = 0.00021858087f + p * w;
    p = -0.00125372503f + p * w;
    p = -0.00417768164f + p * w;
    p = 0.246640727f + p * w;
    p = 1.50140941f + p * w;
  } else {
    w = sqrtf(w) - 3.0f;
    p = -0.000200214257f;
    p = 0.000100950558f + p * w;
    p = 0.00134934322f + p * w;
    p = -0.00367342844f + p * w;
    p = 0.00573950773f + p * w;
    p = -0.0076224613f + p * w;
    p = 0.00943887047f + p * w;
    p = 1.00167406f + p * w;
    p = 2.83297682f + p * w;
  }
  return p * x;
}

__device__ inline float noise_normal(uint32_t i) {
  uint32_t bits = noise_bits(i);
  float f = __uint_as_float((bits >> 9) | 0x3f800000u) - 1.0f;  // [0,1)
  float u = f * 2.0f + (-0.99999994f);   // (hi-lo) RNE-rounds to exactly 2.0f
  u = fmaxf(u, -0.99999994f);
  return 1.41421356237f * xla_erfinv(u); // f32(sqrt(2)) = 0x3FB504F3
}

__device__ inline float softplus_ref(float x) {
  return fmaxf(x, 0.0f) + log1pf(expf(-fabsf(x)));
}

// ---------------- wave(64) primitives ----------------
__device__ inline float wave_max64(float v) {
  #pragma unroll
  for (int off = 32; off; off >>= 1) v = fmaxf(v, __shfl_xor(v, off, 64));
  return v;
}
__device__ inline float wave_sum64(float v) {
  #pragma unroll
  for (int off = 32; off; off >>= 1) v += __shfl_xor(v, off, 64);
  return v;
}
// argmax, tie -> lowest index (stable lax.top_k semantics)
__device__ inline void wave_argmax64(float v, int idx, float& mv, int& mi) {
  float bv = v; int bi = idx;
  #pragma unroll
  for (int off = 32; off; off >>= 1) {
    float ov = __shfl_xor(bv, off, 64);
    int   oi = __shfl_xor(bi, off, 64);
    if (ov > bv || (ov == bv && oi < bi)) { bv = ov; bi = oi; }
  }
  mv = bv; mi = bi;
}

// ---------------- fused: dual GEMM (f32 in, VALU) + router epilogue (f32 out) ----------------
__global__ __launch_bounds__(256)
void NoisyTopKRouter_57621281243491_kernel(
    const float* __restrict__ x, const float* __restrict__ wg,
    const float* __restrict__ wn, float* __restrict__ out) {
  __shared__ float xs[KB][MT + 4];     // x^T tile: xs[k][token]
  __shared__ float wsd[KB][NCOL + 4];  // W^T tile: wsd[k][col]
  __shared__ float lg[MT][NCOL + 4];   // logits: lg[token][col]

  const int tid = threadIdx.x;
  const int tx = tid & 31;    // cols tx*4..tx*4+3
  const int ty = tid >> 5;    // tokens ty*4..ty*4+3
  const int tok0 = blockIdx.x * MT;

  const int lrow = tid >> 3;        // 0..31: token row for x staging
  const int lc4  = (tid & 7) * 4;   // 0..28: k offset for x staging

  float acc[4][4] = {};
  float4 xr, wr0, wr1, wr2, wr3;

  // prologue: stage k-tile 0
  xr = *(const float4*)&x[(size_t)(tok0 + lrow) * DDIM + lc4];
  {
    int r0 = tid >> 3, r1 = (tid + 256) >> 3, r2 = (tid + 512) >> 3, r3 = (tid + 768) >> 3;
    int c = (tid & 7) * 4;
    wr0 = *(const float4*)((r0 < NEXP) ? &wg[(size_t)r0 * DDIM + c] : &wn[(size_t)(r0 - NEXP) * DDIM + c]);
    wr1 = *(const float4*)((r1 < NEXP) ? &wg[(size_t)r1 * DDIM + c] : &wn[(size_t)(r1 - NEXP) * DDIM + c]);
    wr2 = *(const float4*)((r2 < NEXP) ? &wg[(size_t)r2 * DDIM + c] : &wn[(size_t)(r2 - NEXP) * DDIM + c]);
    wr3 = *(const float4*)((r3 < NEXP) ? &wg[(size_t)r3 * DDIM + c] : &wn[(size_t)(r3 - NEXP) * DDIM + c]);
  }
  xs[lc4 + 0][lrow] = xr.x; xs[lc4 + 1][lrow] = xr.y;
  xs[lc4 + 2][lrow] = xr.z; xs[lc4 + 3][lrow] = xr.w;
  {
    int r0 = tid >> 3, r1 = (tid + 256) >> 3, r2 = (tid + 512) >> 3, r3 = (tid + 768) >> 3;
    int c = (tid & 7) * 4;
    wsd[c + 0][r0] = wr0.x; wsd[c + 1][r0] = wr0.y; wsd[c + 2][r0] = wr0.z; wsd[c + 3][r0] = wr0.w;
    wsd[c + 0][r1] = wr1.x; wsd[c + 1][r1] = wr1.y; wsd[c + 2][r1] = wr1.z; wsd[c + 3][r1] = wr1.w;
    wsd[c + 0][r2] = wr2.x; wsd[c + 1][r2] = wr2.y; wsd[c + 2][r2] = wr2.z; wsd[c + 3][r2] = wr2.w;
    wsd[c + 0][r3] = wr3.x; wsd[c + 1][r3] = wr3.y; wsd[c + 2][r3] = wr3.z; wsd[c + 3][r3] = wr3.w;
  }
  __syncthreads();

  const int NT = DDIM / KB;  // 32
  for (int kt = 0; kt < NT; ++kt) {
    if (kt + 1 < NT) {   // prefetch next tile into registers
      const int kn = (kt + 1) * KB;
      xr = *(const float4*)&x[(size_t)(tok0 + lrow) * DDIM + kn + lc4];
      int r0 = tid >> 3, r1 = (tid + 256) >> 3, r2 = (tid + 512) >> 3, r3 = (tid + 768) >> 3;
      int c = (tid & 7) * 4 + kn;
      wr0 = *(const float4*)((r0 < NEXP) ? &wg[(size_t)r0 * DDIM + c] : &wn[(size_t)(r0 - NEXP) * DDIM + c]);
      wr1 = *(const float4*)((r1 < NEXP) ? &wg[(size_t)r1 * DDIM + c] : &wn[(size_t)(r1 - NEXP) * DDIM + c]);
      wr2 = *(const float4*)((r2 < NEXP) ? &wg[(size_t)r2 * DDIM + c] : &wn[(size_t)(r2 - NEXP) * DDIM + c]);
      wr3 = *(const float4*)((r3 < NEXP) ? &wg[(size_t)r3 * DDIM + c] : &wn[(size_t)(r3 - NEXP) * DDIM + c]);
    }
    #pragma unroll
    for (int kk = 0; kk < KB; ++kk) {
      const float4 a = *(const float4*)&xs[kk][ty * 4];
      const float4 b = *(const float4*)&wsd[kk][tx * 4];
      const float av[4] = {a.x, a.y, a.z, a.w};
      const float bv[4] = {b.x, b.y, b.z, b.w};
      #pragma unroll
      for (int i = 0; i < 4; ++i)
        #pragma unroll
        for (int j = 0; j < 4; ++j)
          acc[i][j] += av[i] * bv[j];
    }
    __syncthreads();
    if (kt + 1 < NT) {
      xs[lc4 + 0][lrow] = xr.x; xs[lc4 + 1][lrow] = xr.y;
      xs[lc4 + 2][lrow] = xr.z; xs[lc4 + 3][lrow] = xr.w;
      int r0 = tid >> 3, r1 = (tid + 256) >> 3, r2 = (tid + 512) >> 3, r3 = (tid + 768) >> 3;
      int c = (tid & 7) * 4;
      wsd[c + 0][r0] = wr0.x; wsd[c + 1][r0] = wr0.y; wsd[c + 2][r0] = wr0.z; wsd[c + 3][r0] = wr0.w;
      wsd[c + 0][r1] = wr1.x; wsd[c + 1][r1] = wr1.y; wsd[c + 2][r1] = wr1.z; wsd[c + 3][r1] = wr1.w;
      wsd[c + 0][r2] = wr2.x; wsd[c + 1][r2] = wr2.y; wsd[c + 2][r2] = wr2.z; wsd[c + 3][r2] = wr2.w;
      wsd[c + 0][r3] = wr3.x; wsd[c + 1][r3] = wr3.y; wsd[c + 2][r3] = wr3.z; wsd[c + 3][r3] = wr3.w;
      __syncthreads();
    }
  }

  // dump logits to LDS
  #pragma unroll
  for (int i = 0; i < 4; ++i)
    *(float4*)&lg[ty * 4 + i][tx * 4] =
        make_float4(acc[i][0], acc[i][1], acc[i][2], acc[i][3]);
  __syncthreads();

  // ---- epilogue: one wave per token, lane = expert ----
  const int lane = tid & 63;
  const int w    = tid >> 6;   // wave 0..3

  // f32 output layout (flat element offsets in 1,114,114-element f32 buffer):
  float* out_rw  = out;                        // [16384][2]
  float* out_idx = out + 2 * TOKENS;           // [16384][2] (indices as f32)
  float* out_rp  = out + 4 * TOKENS + 1;       // [16384][64] (after loss scalar)

  float ps_acc = 0.0f, sp_acc = 0.0f, c_acc = 0.0f;

  for (int it = 0; it < MT / 4; ++it) {
    const int tok = w * (MT / 4) + it;
    const int t   = tok0 + tok;
    const float cl = lg[tok][lane];
    const float nl = lg[tok][NEXP + lane];

    // router_probs = softmax(clean)
    const float m  = wave_max64(cl);
    const float v  = expf(cl - m);
    const float Z  = wave_sum64(v);
    const float rp = v / Z;
    out_rp[(size_t)t * NEXP + lane] = rp;
    ps_acc += rp;

    // noisy logits
    const float ns  = softplus_ref(nl);
    sp_acc += ns;
    const float noi = noise_normal((uint32_t)(t * NEXP + lane));
    const float lgn = __fadd_rn(cl, __fmul_rn(noi, ns));

    const float m2 = wave_max64(lgn);
    const float v2 = expf(lgn - m2);
    const float Z2 = wave_sum64(v2);
    const float p  = v2 / Z2;

    float p1; int i1;
    wave_argmax64(p, lane, p1, i1);
    const float pm = (lane == i1) ? -3.402823466e38f : p;
    float p2; int i2;
    wave_argmax64(pm, lane, p2, i2);

    c_acc += (float)((lane == i1) + (lane == i2));

    if (lane == 0) {
      const float s = p1 + p2;
      out_rw[t * 2 + 0]  = p1 / s;
      out_rw[t * 2 + 1]  = p2 / s;
      out_idx[t * 2 + 0] = (float)i1;
      out_idx[t * 2 + 1] = (float)i2;
    }
  }

  // combine 4 waves' partials; write this block's slot (overwritten every call)
  __shared__ float lps[4][NEXP];
  __shared__ float lcb[4][NEXP];
  __shared__ float lspw[4];
  lps[w][lane] = ps_acc;
  lcb[w][lane] = c_acc;
  const float spw = wave_sum64(sp_acc);
  if (lane == 0) lspw[w] = spw;
  __syncthreads();
  if (tid < NEXP) {
    g_ps[blockIdx.x][tid]  = lps[0][tid] + lps[1][tid] + lps[2][tid] + lps[3][tid];
    g_cnt[blockIdx.x][tid] = lcb[0][tid] + lcb[1][tid] + lcb[2][tid] + lcb[3][tid];
  }
  if (tid == 0) g_sp[blockIdx.x] = lspw[0] + lspw[1] + lspw[2] + lspw[3];
}

// ---------------- finalize: loss + noise_scale_mean ----------------
__global__ __launch_bounds__(256)
void finalize_kernel(float* __restrict__ out) {
  const int tid = threadIdx.x, lane = tid & 63, q = tid >> 6;
  float s = 0.0f, c = 0.0f;
  for (int b = q * (NBLK / 4); b < (q + 1) * (NBLK / 4); ++b) {
    s += g_ps[b][lane];
    c += g_cnt[b][lane];
  }
  __shared__ float ss[4][NEXP];
  __shared__ float cc[4][NEXP];
  __shared__ float spw[4];
  ss[q][lane] = s; cc[q][lane] = c;
  float v = g_sp[tid] + g_sp[tid + 256];
  v = wave_sum64(v);
  if (lane == 0) spw[q] = v;
  __syncthreads();
  if (tid < NEXP) {
    const float st = ss[0][tid] + ss[1][tid] + ss[2][tid] + ss[3][tid];
    const float ct = cc[0][tid] + cc[1][tid] + cc[2][tid] + cc[3][tid];
    float term = (ct / (float)TOKENS) * (st / (float)TOKENS);
    term = wave_sum64(term);
    if (tid == 0) {
      out[4 * TOKENS] = 0.64f * term;   // LOAD_BALANCE_WEIGHT * NUM_EXPERTS
      out[4 * TOKENS + 1 + TOKENS * NEXP] =
          (spw[0] + spw[1] + spw[2] + spw[3]) / (float)(TOKENS * NEXP);
    }
  }
}

// ---------------- host ----------------
extern "C" void kernel_launch(void* const* d_in, const int* in_sizes, int n_in,
                              void* d_out, int out_size, void* d_ws, size_t ws_size,
                              hipStream_t stream) {
  const float* x  = (const float*)d_in[0];   // f32 [4,4096,1024]
  const float* wg = (const float*)d_in[1];   // f32 [64,1024]
  const float* wn = (const float*)d_in[2];   // f32 [64,1024]
  float* out = (float*)d_out;                // f32, 1114114 elements

  (void)d_ws; (void)ws_size;   // no workspace used

  NoisyTopKRouter_57621281243491_kernel<<<NBLK, 256, 0, stream>>>(x, wg, wn, out);
  finalize_kernel<<<1, 256, 0, stream>>>(out);
}